// Round 6
// baseline (358.812 us; speedup 1.0000x reference)
//
#include <hip/hip_runtime.h>
#include <hip/hip_bf16.h>

typedef __attribute__((ext_vector_type(8))) short bf16x8;
typedef __attribute__((ext_vector_type(4))) float f32x4;

#define D        256
#define NH       512
#define NT       32               // n-tiles (16 cols each)
#define KT       8                // k-steps (32 each)
#define MT       2                // M-tiles per wave -> 32 rows/wave
#define WAVES    2                // 128-thread blocks, 64 rows/block
#define ROWS_PER_WAVE  32
#define ROWS_PER_BLOCK 64
#define ROWS_TOTAL (32*8192)      // 262144

typedef __attribute__((address_space(1))) const void GV;
typedef __attribute__((address_space(3))) void LV;

__device__ __forceinline__ short f2bf(float f) {
    union { float f; unsigned u; } v; v.f = f;
    unsigned r = v.u + 0x7FFFu + ((v.u >> 16) & 1u);
    return (short)(r >> 16);
}
__device__ __forceinline__ float bf2f(short s) {
    union { unsigned u; float f; } v;
    v.u = ((unsigned)(unsigned short)s) << 16;
    return v.f;
}
__device__ __forceinline__ float rcp_fast(float x) {
    return __builtin_amdgcn_rcpf(x);
}

// Pack We (fp32 [256][512]) into bf16 MFMA B-fragments:
// frag[(nt*8+kt)*64 + lane][j] = We[kt*32 + (lane>>4)*8 + j][nt*16 + (lane&15)]
// Also: bias2[n] = 2*be[n]; Ssum = sum(Wr).
__global__ void prepack_B(const float* __restrict__ We, const float* __restrict__ be,
                          const float* __restrict__ Wr,
                          short* __restrict__ Bh, float* __restrict__ bias2,
                          float* __restrict__ Ssum) {
    int i = blockIdx.x * 256 + threadIdx.x;      // 131072 elements
    int k = i >> 9;
    int n = i & 511;
    int nt = n >> 4, c = n & 15;
    int kt = k >> 5, g = (k >> 3) & 3, j = k & 7;
    int idx = (((nt * 8 + kt) * 64) + (g * 16 + c)) * 8 + j;
    Bh[idx] = f2bf(We[i]);
    if (i < 512) bias2[i] = 2.0f * be[i];
    if (i == 0) {
        float s = 0.0f;
        for (int t = 0; t < 512; ++t) s += Wr[t];
        Ssum[0] = s;
    }
}

__global__ __launch_bounds__(128, 4) void softpool_main(
    const float* __restrict__ x, const short* __restrict__ Bh,
    const float* __restrict__ bias2, const float* __restrict__ Wr,
    const float* __restrict__ br, const float* __restrict__ Ssum,
    float* __restrict__ out)
{
    const int lane = threadIdx.x & 63;
    const int wave = threadIdx.x >> 6;           // 0..1
    const int c = lane & 15;     // A row-in-tile / C col / B col
    const int g = lane >> 4;     // k-group
    const long row0 = (long)blockIdx.x * ROWS_PER_BLOCK + (long)wave * ROWS_PER_WAVE;

    __shared__ short Bl[2][4096];   // 2 x 8KB double buffer (one nt each)

    // Wave stages kt = 4*wave .. 4*wave+3 (1KB each) of the nt-tile.
    const int kt0 = wave * 4;
    const short* gB = Bh + (long)kt0 * 512 + lane * 8;

    #define STAGE(buf, ntv) {                                                  \
        const short* _g = gB + (long)(ntv) * 4096;                             \
        _Pragma("unroll")                                                      \
        for (int kk = 0; kk < 4; ++kk)                                         \
            __builtin_amdgcn_global_load_lds((GV*)(_g + kk * 512),             \
                (LV*)&Bl[buf][(kt0 + kk) * 512], 16, 0, 0);                    \
    }

    STAGE(0, 0)   // prologue staging, lands during the A HBM loads

    // ---- Load A fragments (2 Mtiles x 8 k-steps), fp32 -> bf16, keep in regs
    bf16x8 a[MT][KT];
    #pragma unroll
    for (int m = 0; m < MT; ++m) {
        const float* xr = x + (row0 + m * 16 + c) * D + g * 8;
        #pragma unroll
        for (int kt = 0; kt < KT; ++kt) {
            float4 v0 = *(const float4*)(xr + kt * 32);
            float4 v1 = *(const float4*)(xr + kt * 32 + 4);
            bf16x8 t;
            t[0] = f2bf(v0.x); t[1] = f2bf(v0.y); t[2] = f2bf(v0.z); t[3] = f2bf(v0.w);
            t[4] = f2bf(v1.x); t[5] = f2bf(v1.y); t[6] = f2bf(v1.z); t[7] = f2bf(v1.w);
            a[m][kt] = t;
        }
    }

    // lps[m][r] accumulates sum_n Wr[n] * rcp(exp(2*y)+1); logit = S - 2*lps + br
    float lps[MT][4];
    #pragma unroll
    for (int m = 0; m < MT; ++m)
        #pragma unroll
        for (int r = 0; r < 4; ++r) lps[m][r] = 0.0f;

    f32x4 accA[MT], accB[MT];

    #define MFMA(buf, accv) {                                                  \
        _Pragma("unroll")                                                      \
        for (int m = 0; m < MT; ++m)                                           \
            _Pragma("unroll")                                                  \
            for (int r = 0; r < 4; ++r) accv[m][r] = 0.0f;                     \
        _Pragma("unroll")                                                      \
        for (int kt = 0; kt < KT; ++kt) {                                      \
            bf16x8 b = *(const bf16x8*)&Bl[buf][kt * 512 + lane * 8];          \
            _Pragma("unroll")                                                  \
            for (int m = 0; m < MT; ++m)                                       \
                accv[m] = __builtin_amdgcn_mfma_f32_16x16x32_bf16(             \
                             a[m][kt], b, accv[m], 0, 0, 0);                   \
        }                                                                      \
    }

    #define TANH(accv, ntv) {                                                  \
        int n = (ntv) * 16 + c;                                                \
        float b2 = bias2[n];                                                   \
        float vr = Wr[n];                                                      \
        _Pragma("unroll")                                                      \
        for (int m = 0; m < MT; ++m)                                           \
            _Pragma("unroll")                                                  \
            for (int r = 0; r < 4; ++r) {                                      \
                float z = __builtin_fmaf(accv[m][r], 2.0f, b2);                \
                float e = __expf(z);                                           \
                float rr = rcp_fast(e + 1.0f);                                 \
                lps[m][r] = __builtin_fmaf(vr, rr, lps[m][r]);                 \
            }                                                                  \
    }

    __syncthreads();          // nt=0 staged

    // phase 0: compute accA(nt0), stage nt1
    STAGE(1, 1)
    MFMA(0, accA)
    __syncthreads();

    // phases 1..30 in pairs; TANH runs one phase behind its MFMA
    for (int it = 0; it < 15; ++it) {
        const int p1 = 2 * it + 1;      // odd phase, buf1 -> accB
        STAGE(0, p1 + 1)
        MFMA(1, accB)
        TANH(accA, p1 - 1)
        __syncthreads();
        const int p2 = 2 * it + 2;      // even phase, buf0 -> accA
        STAGE(1, p2 + 1)                // p2+1 <= 31 always
        MFMA(0, accA)
        TANH(accB, p2 - 1)
        __syncthreads();
    }

    // phase 31 (buf1) + drain both accs
    MFMA(1, accB)
    TANH(accA, 30)
    TANH(accB, 31)

    // ---- Reduce partial sums over 16 cols; softmax(sigmoid); in-register output
    const float brv = br[0];
    const float S = Ssum[0];
    #pragma unroll
    for (int m = 0; m < MT; ++m) {
        float l0 = lps[m][0], l1 = lps[m][1], l2 = lps[m][2], l3 = lps[m][3];
        #pragma unroll
        for (int off = 1; off < 16; off <<= 1) {
            l0 += __shfl_xor(l0, off, 64);
            l1 += __shfl_xor(l1, off, 64);
            l2 += __shfl_xor(l2, off, 64);
            l3 += __shfl_xor(l3, off, 64);
        }
        // logits of window (m, g): rows m*16 + g*4 + r
        float g0 = S - 2.0f * l0 + brv;
        float g1 = S - 2.0f * l1 + brv;
        float g2 = S - 2.0f * l2 + brv;
        float g3 = S - 2.0f * l3 + brv;
        float s0 = rcp_fast(1.0f + __expf(-g0));
        float s1 = rcp_fast(1.0f + __expf(-g1));
        float s2 = rcp_fast(1.0f + __expf(-g2));
        float s3 = rcp_fast(1.0f + __expf(-g3));
        float e0 = __expf(s0), e1 = __expf(s1), e2 = __expf(s2), e3 = __expf(s3);
        float inv = rcp_fast(e0 + e1 + e2 + e3);
        float w0 = e0 * inv, w1 = e1 * inv, w2 = e2 * inv, w3 = e3 * inv;

        // Broadcast weights of window (m, c>>2) to the lanes holding its rows:
        // A-frag lane (g,c) holds row m*16+c; its window is c>>2, position c&3.
        const int srcLane = ((c >> 2) << 4) | c;   // lane (g'=c>>2, c'=c)
        float b0 = __shfl(w0, srcLane, 64);
        float b1 = __shfl(w1, srcLane, 64);
        float b2w = __shfl(w2, srcLane, 64);
        float b3 = __shfl(w3, srcLane, 64);
        // select this row's weight by c&3
        float wlo = (c & 2) ? b2w : b0;
        float whi = (c & 2) ? b3 : b1;
        float wsel = (c & 1) ? whi : wlo;

        // out[W][d] = sum over the 4 rows of the window (fold over c bits 0,1)
        const long outRow = (row0 >> 2) + m * 4 + (c >> 2);
        float* op = out + outRow * D + g * 8;
        #pragma unroll
        for (int kt = 0; kt < KT; ++kt) {
            float p0 = wsel * bf2f(a[m][kt][0]);
            float p1v = wsel * bf2f(a[m][kt][1]);
            float p2v = wsel * bf2f(a[m][kt][2]);
            float p3v = wsel * bf2f(a[m][kt][3]);
            float p4 = wsel * bf2f(a[m][kt][4]);
            float p5 = wsel * bf2f(a[m][kt][5]);
            float p6 = wsel * bf2f(a[m][kt][6]);
            float p7 = wsel * bf2f(a[m][kt][7]);
            p0 += __shfl_xor(p0, 1, 64); p0 += __shfl_xor(p0, 2, 64);
            p1v += __shfl_xor(p1v, 1, 64); p1v += __shfl_xor(p1v, 2, 64);
            p2v += __shfl_xor(p2v, 1, 64); p2v += __shfl_xor(p2v, 2, 64);
            p3v += __shfl_xor(p3v, 1, 64); p3v += __shfl_xor(p3v, 2, 64);
            p4 += __shfl_xor(p4, 1, 64); p4 += __shfl_xor(p4, 2, 64);
            p5 += __shfl_xor(p5, 1, 64); p5 += __shfl_xor(p5, 2, 64);
            p6 += __shfl_xor(p6, 1, 64); p6 += __shfl_xor(p6, 2, 64);
            p7 += __shfl_xor(p7, 1, 64); p7 += __shfl_xor(p7, 2, 64);
            if ((c & 3) == 0) {
                float4 lo = make_float4(p0, p1v, p2v, p3v);
                float4 hi = make_float4(p4, p5, p6, p7);
                *(float4*)(op + kt * 32) = lo;
                *(float4*)(op + kt * 32 + 4) = hi;
            }
        }
    }
}

extern "C" void kernel_launch(void* const* d_in, const int* in_sizes, int n_in,
                              void* d_out, int out_size, void* d_ws, size_t ws_size,
                              hipStream_t stream) {
    const float* x  = (const float*)d_in[0];
    const float* We = (const float*)d_in[1];
    const float* be = (const float*)d_in[2];
    const float* Wr = (const float*)d_in[3];
    const float* br = (const float*)d_in[4];
    float* out = (float*)d_out;

    char* ws = (char*)d_ws;
    short* Bh    = (short*)ws;                    // 262144 B
    float* bias2 = (float*)(ws + 262144);         // 2048 B
    float* Ssum  = (float*)(ws + 262144 + 2048);  // 4 B

    prepack_B<<<NH * D / 256, 256, 0, stream>>>(We, be, Wr, Bh, bias2, Ssum);

    const int blocks = ROWS_TOTAL / ROWS_PER_BLOCK;   // 4096
    softpool_main<<<blocks, 128, 0, stream>>>(x, Bh, bias2, Wr, br, Ssum, out);
}

// Round 7
// 161.808 us; speedup vs baseline: 2.2175x; 2.2175x over previous
//
#include <hip/hip_runtime.h>
#include <hip/hip_bf16.h>

typedef __attribute__((ext_vector_type(8))) short bf16x8;
typedef __attribute__((ext_vector_type(4))) float f32x4;

#define D        256
#define NH       512
#define NT       32               // n-tiles (16 cols each)
#define KT       8                // k-steps (32 each)
#define MT       4                // M-tiles per wave -> 64 rows/wave
#define ROWS_PER_BLOCK 64         // 1 wave per block
#define ROWS_TOTAL (32*8192)      // 262144

typedef __attribute__((address_space(1))) const void GV;
typedef __attribute__((address_space(3))) void LV;

__device__ __forceinline__ short f2bf(float f) {
    union { float f; unsigned u; } v; v.f = f;
    unsigned r = v.u + 0x7FFFu + ((v.u >> 16) & 1u);
    return (short)(r >> 16);
}
__device__ __forceinline__ float rcp_fast(float x) {
    return __builtin_amdgcn_rcpf(x);
}

// Pack We (fp32 [256][512]) into bf16 MFMA B-fragments:
// frag[(nt*8+kt)*64 + lane][j] = We[kt*32 + (lane>>4)*8 + j][nt*16 + (lane&15)]
// Also: bias2[n] = 2*be[n]; Ssum = sum(Wr).
__global__ void prepack_B(const float* __restrict__ We, const float* __restrict__ be,
                          const float* __restrict__ Wr,
                          short* __restrict__ Bh, float* __restrict__ bias2,
                          float* __restrict__ Ssum) {
    int i = blockIdx.x * 256 + threadIdx.x;      // 131072 elements
    int k = i >> 9;
    int n = i & 511;
    int nt = n >> 4, c = n & 15;
    int kt = k >> 5, g = (k >> 3) & 3, j = k & 7;
    int idx = (((nt * 8 + kt) * 64) + (g * 16 + c)) * 8 + j;
    Bh[idx] = f2bf(We[i]);
    if (i < 512) bias2[i] = 2.0f * be[i];
    if (i == 0) {
        float s = 0.0f;
        for (int t = 0; t < 512; ++t) s += Wr[t];
        Ssum[0] = s;
    }
}

// 1-wave blocks: barrier-free LDS double-buffer with counted vmcnt waits.
__global__ __launch_bounds__(64, 2) void softpool_main(
    const float* __restrict__ x, const short* __restrict__ Bh,
    const float* __restrict__ bias2, const float* __restrict__ Wr,
    const float* __restrict__ br, const float* __restrict__ Ssum,
    float* __restrict__ out)
{
    const int lane = threadIdx.x;        // 0..63
    const int c = lane & 15;             // A row-in-tile / C col / B col
    const int g = lane >> 4;             // k-group
    const long row0 = (long)blockIdx.x * ROWS_PER_BLOCK;

    __shared__ short Bl[2][4096];        // 2 x 8KB double buffer (one nt each)

    const short* gB = Bh + lane * 8;

    // Stage one full nt-tile (8KB) into Bl[buf]: 8 x global_load_lds width=16.
    #define STAGE(buf, ntv) {                                                  \
        const short* _g = gB + (long)(ntv) * 4096;                             \
        _Pragma("unroll")                                                      \
        for (int kk = 0; kk < 8; ++kk)                                         \
            __builtin_amdgcn_global_load_lds((GV*)(_g + kk * 512),             \
                (LV*)&Bl[buf][kk * 512], 16, 0, 0);                            \
    }

    STAGE(0, 0)   // in flight during the A HBM loads

    // ---- Load A fragments (4 Mtiles x 8 k-steps), fp32 -> bf16, keep in regs
    bf16x8 a[MT][KT];
    #pragma unroll
    for (int m = 0; m < MT; ++m) {
        const float* xr = x + (row0 + m * 16 + c) * D + g * 8;
        #pragma unroll
        for (int kt = 0; kt < KT; ++kt) {
            float4 v0 = *(const float4*)(xr + kt * 32);
            float4 v1 = *(const float4*)(xr + kt * 32 + 4);
            bf16x8 t;
            t[0] = f2bf(v0.x); t[1] = f2bf(v0.y); t[2] = f2bf(v0.z); t[3] = f2bf(v0.w);
            t[4] = f2bf(v1.x); t[5] = f2bf(v1.y); t[6] = f2bf(v1.z); t[7] = f2bf(v1.w);
            a[m][kt] = t;
        }
    }

    // lps[m][r] accumulates sum_n Wr[n]*rcp(exp(2y)+1); logit = S - 2*lps + br
    float lps[MT][4];
    #pragma unroll
    for (int m = 0; m < MT; ++m)
        #pragma unroll
        for (int r = 0; r < 4; ++r) lps[m][r] = 0.0f;

    f32x4 accA[MT], accB[MT];

    #define MFMA_(buf, accv) {                                                 \
        _Pragma("unroll")                                                      \
        for (int m = 0; m < MT; ++m)                                           \
            _Pragma("unroll")                                                  \
            for (int r = 0; r < 4; ++r) accv[m][r] = 0.0f;                     \
        _Pragma("unroll")                                                      \
        for (int kt = 0; kt < KT; ++kt) {                                      \
            bf16x8 b = *(const bf16x8*)&Bl[buf][kt * 512 + lane * 8];          \
            _Pragma("unroll")                                                  \
            for (int m = 0; m < MT; ++m)                                       \
                accv[m] = __builtin_amdgcn_mfma_f32_16x16x32_bf16(             \
                             a[m][kt], b, accv[m], 0, 0, 0);                   \
        }                                                                      \
    }

    #define TANH_(accv, ntv) {                                                 \
        int n = (ntv) * 16 + c;                                                \
        float b2 = bias2[n];                                                   \
        float vr = Wr[n];                                                      \
        _Pragma("unroll")                                                      \
        for (int m = 0; m < MT; ++m)                                           \
            _Pragma("unroll")                                                  \
            for (int r = 0; r < 4; ++r) {                                      \
                float z = __builtin_fmaf(accv[m][r], 2.0f, b2);                \
                float e = __expf(z);                                           \
                float rr = rcp_fast(e + 1.0f);                                 \
                lps[m][r] = __builtin_fmaf(vr, rr, lps[m][r]);                 \
            }                                                                  \
    }

    #define WAITV0 asm volatile("s_waitcnt vmcnt(0)" ::: "memory");

    WAITV0            // nt=0 staged (A loads also drained)

    // nt=0 (buf0 -> accA)
    STAGE(1, 1)
    MFMA_(0, accA)
    WAITV0
    // nt = 1..30 in pairs; TANH runs one phase behind its MFMA
    for (int it = 0; it < 15; ++it) {
        const int ntB = 2 * it + 1;          // odd nt, buf1 -> accB
        STAGE(0, ntB + 1)
        MFMA_(1, accB)
        TANH_(accA, ntB - 1)
        WAITV0
        const int ntA = 2 * it + 2;          // even nt, buf0 -> accA
        STAGE(1, ntA + 1)                    // ntA+1 <= 31 always
        MFMA_(0, accA)
        TANH_(accB, ntA - 1)
        WAITV0
    }
    // nt=31 (buf1) + drain
    MFMA_(1, accB)
    TANH_(accA, 30)
    TANH_(accB, 31)

    // ---- Reduce partials over 16 cols; softmax(sigmoid); weighted output
    const float brv = br[0];
    const float S = Ssum[0];
    #pragma unroll
    for (int m = 0; m < MT; ++m) {
        float l0 = lps[m][0], l1 = lps[m][1], l2 = lps[m][2], l3 = lps[m][3];
        #pragma unroll
        for (int off = 1; off < 16; off <<= 1) {
            l0 += __shfl_xor(l0, off, 64);
            l1 += __shfl_xor(l1, off, 64);
            l2 += __shfl_xor(l2, off, 64);
            l3 += __shfl_xor(l3, off, 64);
        }
        float g0 = S - 2.0f * l0 + brv;
        float g1 = S - 2.0f * l1 + brv;
        float g2 = S - 2.0f * l2 + brv;
        float g3 = S - 2.0f * l3 + brv;
        float s0 = rcp_fast(1.0f + __expf(-g0));
        float s1 = rcp_fast(1.0f + __expf(-g1));
        float s2 = rcp_fast(1.0f + __expf(-g2));
        float s3 = rcp_fast(1.0f + __expf(-g3));
        float e0 = __expf(s0), e1 = __expf(s1), e2 = __expf(s2), e3 = __expf(s3);
        float inv = rcp_fast(e0 + e1 + e2 + e3);
        float w0 = e0 * inv, w1 = e1 * inv, w2 = e2 * inv, w3 = e3 * inv;

        // window = rows [wrow, wrow+3]; lane-group g owns window g of this Mtile
        // lane stores cols [c*4 + q*64 ..+3]: 16 lanes -> 256B contiguous runs
        const long wrow = row0 + m * 16 + g * 4;
        const long W = wrow >> 2;
        const float* xw = x + wrow * D + c * 4;
        float* op = out + W * D + c * 4;
        #pragma unroll
        for (int q = 0; q < 4; ++q) {
            float4 r0 = *(const float4*)(xw + 0 * D + q * 64);
            float4 r1 = *(const float4*)(xw + 1 * D + q * 64);
            float4 r2 = *(const float4*)(xw + 2 * D + q * 64);
            float4 r3 = *(const float4*)(xw + 3 * D + q * 64);
            float4 oo;
            oo.x = w0 * r0.x + w1 * r1.x + w2 * r2.x + w3 * r3.x;
            oo.y = w0 * r0.y + w1 * r1.y + w2 * r2.y + w3 * r3.y;
            oo.z = w0 * r0.z + w1 * r1.z + w2 * r2.z + w3 * r3.z;
            oo.w = w0 * r0.w + w1 * r1.w + w2 * r2.w + w3 * r3.w;
            *(float4*)(op + q * 64) = oo;
        }
    }
}

extern "C" void kernel_launch(void* const* d_in, const int* in_sizes, int n_in,
                              void* d_out, int out_size, void* d_ws, size_t ws_size,
                              hipStream_t stream) {
    const float* x  = (const float*)d_in[0];
    const float* We = (const float*)d_in[1];
    const float* be = (const float*)d_in[2];
    const float* Wr = (const float*)d_in[3];
    const float* br = (const float*)d_in[4];
    float* out = (float*)d_out;

    char* ws = (char*)d_ws;
    short* Bh    = (short*)ws;                    // 262144 B
    float* bias2 = (float*)(ws + 262144);         // 2048 B
    float* Ssum  = (float*)(ws + 262144 + 2048);  // 4 B

    prepack_B<<<NH * D / 256, 256, 0, stream>>>(We, be, Wr, Bh, bias2, Ssum);

    const int blocks = ROWS_TOTAL / ROWS_PER_BLOCK;   // 4096
    softpool_main<<<blocks, 64, 0, stream>>>(x, Bh, bias2, Wr, br, Ssum, out);
}